// Round 1
// baseline (116.051 us; speedup 1.0000x reference)
//
#include <hip/hip_runtime.h>
#include <cmath>

#ifndef M_PI
#define M_PI 3.14159265358979323846
#endif

static constexpr int CH    = 128;   // channels
static constexpr int NBATCH= 64;    // batch
static constexpr int HWSZ  = 3136;  // 56*56
static constexpr int HW4   = 784;   // HWSZ/4
static constexpr int PARTS = 16;    // chunks per channel
static constexpr int SLPP  = NBATCH / PARTS; // 4 batch-slices per chunk
static constexpr int KTOP  = 10;
static constexpr float EPSV = 1e-5f;

// compare-swap keeping (a,b) ascending  (a<=b)
#define CSA(a,b) { float lo_=fminf(a,b), hi_=fmaxf(a,b); a=lo_; b=hi_; }
// compare-swap keeping (a,b) descending (a>=b)
#define CSD(a,b) { float hi_=fmaxf(a,b), lo_=fminf(a,b); a=hi_; b=lo_; }

// insert v into top-list (t0..t9 ascending, t0=min gate) and bottom-list
// (b0..b9 descending, b0=max gate)
#define INSERT(v) do {                                                   \
  if ((v) > t0) { t0=(v); CSA(t0,t1);CSA(t1,t2);CSA(t2,t3);CSA(t3,t4);   \
                  CSA(t4,t5);CSA(t5,t6);CSA(t6,t7);CSA(t7,t8);CSA(t8,t9);} \
  if ((v) < b0) { b0=(v); CSD(b0,b1);CSD(b1,b2);CSD(b2,b3);CSD(b3,b4);   \
                  CSD(b4,b5);CSD(b5,b6);CSD(b6,b7);CSD(b7,b8);CSD(b8,b9);} \
} while (0)

// ---------------------------------------------------------------------------
// Kernel A: per (part, channel) block: partial sum + top-10 + bottom-10 of x
// grid = PARTS*CH = 2048 blocks, 256 threads
// ---------------------------------------------------------------------------
__global__ __launch_bounds__(256) void kA(const float* __restrict__ x,
                                          float* __restrict__ sums,
                                          float* __restrict__ tops,
                                          float* __restrict__ bots) {
  const int bid  = blockIdx.x;
  const int c    = bid & (CH - 1);
  const int part = bid >> 7;
  const int tid  = threadIdx.x;
  const float4* x4 = reinterpret_cast<const float4*>(x);

  float s = 0.f;
  float t0=-3.402823e38f,t1=t0,t2=t0,t3=t0,t4=t0,t5=t0,t6=t0,t7=t0,t8=t0,t9=t0;
  float b0= 3.402823e38f,b1=b0,b2=b0,b3=b0,b4=b0,b5=b0,b6=b0,b7=b0,b8=b0,b9=b0;

  for (int sl = 0; sl < SLPP; ++sl) {
    const int n = part * SLPP + sl;
    const size_t base = (size_t)(n * CH + c) * HW4;
    for (int i = tid; i < HW4; i += 256) {
      float4 v = x4[base + i];
      s += (v.x + v.y) + (v.z + v.w);
      INSERT(v.x); INSERT(v.y); INSERT(v.z); INSERT(v.w);
    }
  }

  // ---- block sum reduce ----
  for (int off = 32; off; off >>= 1) s += __shfl_down(s, off);
  __shared__ float sh4[4];
  __shared__ float swv[4];
  __shared__ int   swi[4];
  const int lane = tid & 63, wid = tid >> 6;
  if (lane == 0) sh4[wid] = s;

  // ---- dump per-thread candidates to LDS (strided: bank-conflict free) ----
  __shared__ float shT[KTOP * 256];
  __shared__ float shB[KTOP * 256];
  shT[0*256+tid]=t0; shT[1*256+tid]=t1; shT[2*256+tid]=t2; shT[3*256+tid]=t3;
  shT[4*256+tid]=t4; shT[5*256+tid]=t5; shT[6*256+tid]=t6; shT[7*256+tid]=t7;
  shT[8*256+tid]=t8; shT[9*256+tid]=t9;
  shB[0*256+tid]=b0; shB[1*256+tid]=b1; shB[2*256+tid]=b2; shB[3*256+tid]=b3;
  shB[4*256+tid]=b4; shB[5*256+tid]=b5; shB[6*256+tid]=b6; shB[7*256+tid]=b7;
  shB[8*256+tid]=b8; shB[9*256+tid]=b9;
  __syncthreads();
  if (tid == 0) sums[bid] = (sh4[0] + sh4[1]) + (sh4[2] + sh4[3]);

  // ---- extract block top-10 (max-extraction, 10 iterations) ----
  for (int it = 0; it < KTOP; ++it) {
    float best = -3.402823e38f; int bi = -1;
    #pragma unroll
    for (int j = 0; j < KTOP; ++j) {
      float v = shT[j*256 + tid];
      if (v > best) { best = v; bi = j*256 + tid; }
    }
    for (int off = 32; off; off >>= 1) {
      float ov = __shfl_down(best, off);
      int   oi = __shfl_down(bi, off);
      if (ov > best) { best = ov; bi = oi; }
    }
    if (lane == 0) { swv[wid] = best; swi[wid] = bi; }
    __syncthreads();
    if (tid == 0) {
      float bb = swv[0]; int bbi = swi[0];
      for (int w = 1; w < 4; ++w) if (swv[w] > bb) { bb = swv[w]; bbi = swi[w]; }
      tops[bid * KTOP + it] = bb;
      shT[bbi] = -3.402823e38f;
    }
    __syncthreads();
  }

  // ---- extract block bottom-10 (min-extraction) ----
  for (int it = 0; it < KTOP; ++it) {
    float best = 3.402823e38f; int bi = -1;
    #pragma unroll
    for (int j = 0; j < KTOP; ++j) {
      float v = shB[j*256 + tid];
      if (v < best) { best = v; bi = j*256 + tid; }
    }
    for (int off = 32; off; off >>= 1) {
      float ov = __shfl_down(best, off);
      int   oi = __shfl_down(bi, off);
      if (ov < best) { best = ov; bi = oi; }
    }
    if (lane == 0) { swv[wid] = best; swi[wid] = bi; }
    __syncthreads();
    if (tid == 0) {
      float bb = swv[0]; int bbi = swi[0];
      for (int w = 1; w < 4; ++w) if (swv[w] < bb) { bb = swv[w]; bbi = swi[w]; }
      bots[bid * KTOP + it] = bb;
      shB[bbi] = 3.402823e38f;
    }
    __syncthreads();
  }
}

// ---------------------------------------------------------------------------
// Kernel B: per channel: mean, exact top-10 of |v-mean| from 320 candidates,
// fold into (sw, sb).  grid = CH blocks, 64 threads
// ---------------------------------------------------------------------------
__global__ __launch_bounds__(64) void kB(const float* __restrict__ sums,
                                         const float* __restrict__ tops,
                                         const float* __restrict__ bots,
                                         const float* __restrict__ weight,
                                         const float* __restrict__ bias,
                                         float* __restrict__ sw,
                                         float* __restrict__ sb,
                                         float constv) {
  const int c   = blockIdx.x;
  const int tid = threadIdx.x;

  float ps = 0.f;
  if (tid < PARTS) ps = sums[tid * CH + c];
  for (int off = 32; off; off >>= 1) ps += __shfl_down(ps, off);
  const float mu = __shfl(ps, 0) * (1.0f / (NBATCH * HWSZ));

  __shared__ float cd[2 * PARTS * KTOP]; // 320
  for (int j = tid; j < PARTS * KTOP; j += 64) {
    const int part = j / KTOP, it = j % KTOP;
    cd[j]                 = fabsf(tops[(part * CH + c) * KTOP + it] - mu);
    cd[PARTS * KTOP + j]  = fabsf(bots[(part * CH + c) * KTOP + it] - mu);
  }
  __syncthreads();

  float total = 0.f;
  for (int it = 0; it < KTOP; ++it) {
    float best = -1.f; int bi = -1;
    for (int j = tid; j < 2 * PARTS * KTOP; j += 64) {
      float v = cd[j];
      if (v > best) { best = v; bi = j; }
    }
    for (int off = 32; off; off >>= 1) {
      float ov = __shfl_down(best, off);
      int   oi = __shfl_down(bi, off);
      if (ov > best) { best = ov; bi = oi; }
    }
    if (tid == 0) { total += best; cd[bi] = -1.f; }
    __syncthreads();
  }

  if (tid == 0) {
    const float mtk = total * (1.0f / KTOP) * constv;
    const float inv = 1.f / (mtk + EPSV);
    const float w   = inv * weight[c];
    sw[c] = w;
    sb[c] = bias[c] - mu * w;
  }
}

// ---------------------------------------------------------------------------
// Kernel C: out = fma(x, sw[c], sb[c]).  grid = NBATCH*CH slices, 256 threads
// ---------------------------------------------------------------------------
__global__ __launch_bounds__(256) void kC(const float* __restrict__ x,
                                          const float* __restrict__ sw,
                                          const float* __restrict__ sb,
                                          float* __restrict__ out) {
  const int s = blockIdx.x;           // n*CH + c
  const int c = s & (CH - 1);
  const float w = sw[c], b = sb[c];
  const float4* x4 = reinterpret_cast<const float4*>(x) + (size_t)s * HW4;
  float4*       o4 = reinterpret_cast<float4*>(out)     + (size_t)s * HW4;
  for (int i = threadIdx.x; i < HW4; i += 256) {
    float4 v = x4[i];
    float4 r;
    r.x = fmaf(v.x, w, b);
    r.y = fmaf(v.y, w, b);
    r.z = fmaf(v.z, w, b);
    r.w = fmaf(v.w, w, b);
    o4[i] = r;
  }
}

extern "C" void kernel_launch(void* const* d_in, const int* in_sizes, int n_in,
                              void* d_out, int out_size, void* d_ws, size_t ws_size,
                              hipStream_t stream) {
  const float* x      = (const float*)d_in[0];
  const float* weight = (const float*)d_in[1];
  const float* bias   = (const float*)d_in[2];
  float* out = (float*)d_out;
  float* ws  = (float*)d_ws;

  // ws layout (floats)
  float* sums = ws;                       // PARTS*CH              = 2048
  float* tops = sums + PARTS * CH;        // PARTS*CH*KTOP         = 20480
  float* bots = tops + PARTS * CH * KTOP; // PARTS*CH*KTOP         = 20480
  float* sw   = bots + PARTS * CH * KTOP; // CH                    = 128
  float* sb   = sw + CH;                  // CH                    = 128

  const double M = (double)NBATCH * (double)HWSZ;
  const float constv =
      (float)(0.5 * (1.0 + sqrt(M_PI * log(4.0))) / sqrt(2.0 * log(M)));

  kA<<<PARTS * CH, 256, 0, stream>>>(x, sums, tops, bots);
  kB<<<CH, 64, 0, stream>>>(sums, tops, bots, weight, bias, sw, sb, constv);
  kC<<<NBATCH * CH, 256, 0, stream>>>(x, sw, sb, out);
}